// Round 4
// baseline (160.627 us; speedup 1.0000x reference)
//
#include <hip/hip_runtime.h>

#define NB 4096
#define NF 32             // F0 == F1
#define NE 32
#define NI 496            // 32*31/2
#define BN_EPS 1e-5f
#define XPAD 36           // padded row stride (floats): 16B-aligned, bank-rotating

#define SA_BLOCKS 512
#define SA_BPB    8       // batches per stats block
#define SA_CHUNK  4       // batches staged per LDS pass

typedef float f32x4_t __attribute__((ext_vector_type(4)));

// closed-form pair index: offset(r) = r*(63-r)/2
__device__ __forceinline__ void pair_rc_fast(int i, int& r, int& c) {
    int rr = (int)((63.0f - sqrtf(3969.0f - 8.0f * (float)i)) * 0.5f);
    int off = rr * (63 - rr) / 2;
    if (off > i) { --rr; off = rr * (63 - rr) / 2; }
    else {
        int off2 = (rr + 1) * (62 - rr) / 2;
        if (off2 <= i) { rr = rr + 1; off = off2; }
    }
    r = rr; c = rr + 1 + (i - off);
}

// ---- Stats A: partial Gram matrices G1 = sum xi*xj, G2 = sum xi^2*xj^2 -----
// part[blk][ (r*32+c)*2 + {0,1} ]
__global__ __launch_bounds__(256) void statsA(
        const float* __restrict__ xi, const float* __restrict__ xj,
        float* __restrict__ part) {
    __shared__ __attribute__((aligned(16))) float xi_l[SA_CHUNK * NF * XPAD];
    __shared__ __attribute__((aligned(16))) float xj_l[SA_CHUNK * NF * XPAD];
    const int t  = threadIdx.x;
    const int r  = t >> 3;
    const int cg = t & 7;

    float4 acc1[4] = {{0,0,0,0},{0,0,0,0},{0,0,0,0},{0,0,0,0}};
    float4 acc2[4] = {{0,0,0,0},{0,0,0,0},{0,0,0,0},{0,0,0,0}};

    for (int ch = 0; ch < SA_BPB / SA_CHUNK; ++ch) {
        const int b0 = blockIdx.x * SA_BPB + ch * SA_CHUNK;
        const float4* xs = (const float4*)(xi + (size_t)b0 * NF * NE);
        const float4* ys = (const float4*)(xj + (size_t)b0 * NF * NE);
        if (ch) __syncthreads();
        #pragma unroll
        for (int k = 0; k < 4; ++k) {
            const int idx = t + 256 * k;          // 0..1023 float4s
            const int row = idx >> 3;             // bb*32 + feature row
            const int e4  = idx & 7;
            *(float4*)&xi_l[row * XPAD + e4 * 4] = xs[idx];
            *(float4*)&xj_l[row * XPAD + e4 * 4] = ys[idx];
        }
        __syncthreads();
        #pragma unroll
        for (int bb = 0; bb < SA_CHUNK; ++bb) {
            const float* xr  = &xi_l[(bb * NF + r) * XPAD];
            const float* xc0 = &xj_l[(bb * NF) * XPAD];
            #pragma unroll
            for (int e4 = 0; e4 < 8; ++e4) {
                const float4 av = *(const float4*)&xr[e4 * 4];
                #pragma unroll
                for (int k = 0; k < 4; ++k) {
                    const int c = cg + 8 * k;
                    const float4 qv = *(const float4*)&xc0[c * XPAD + e4 * 4];
                    float px = av.x * qv.x, py = av.y * qv.y;
                    float pz = av.z * qv.z, pw = av.w * qv.w;
                    acc1[k].x += px; acc1[k].y += py;
                    acc1[k].z += pz; acc1[k].w += pw;
                    acc2[k].x += px * px; acc2[k].y += py * py;
                    acc2[k].z += pz * pz; acc2[k].w += pw * pw;
                }
            }
        }
    }

    float* dst = part + (size_t)blockIdx.x * 2048;
    #pragma unroll
    for (int k = 0; k < 4; ++k) {
        const int c = cg + 8 * k;
        const int j = r * 32 + c;
        float g1 = (acc1[k].x + acc1[k].y) + (acc1[k].z + acc1[k].w);
        float g2 = (acc2[k].x + acc2[k].y) + (acc2[k].z + acc2[k].w);
        *(float2*)&dst[2 * j] = make_float2(g1, g2);
    }
}

// ---- Stats B: reduce partials + finalize scale/shift ------------------------
__global__ __launch_bounds__(256) void statsB(
        const float* __restrict__ part,
        const float* __restrict__ gamma, const float* __restrict__ beta,
        float* __restrict__ scale, float* __restrict__ shift) {
    __shared__ float sums[256];
    const int t = threadIdx.x;
    const int base = blockIdx.x * 256;
    float s = 0.f;
    #pragma unroll 4
    for (int p = 0; p < SA_BLOCKS; ++p)
        s += part[(size_t)p * 2048 + base + t];
    sums[t] = s;
    __syncthreads();
    if (t < 128) {
        const int q = blockIdx.x * 128 + t;      // rc index 0..1023
        const int r = q >> 5, c = q & 31;
        if (c > r) {
            const float g1 = sums[2 * t];
            const float g2 = sums[2 * t + 1];
            const float invN = 1.0f / (float)(NB * NE);
            const float mean = g1 * invN;
            const float var  = g2 * invN - mean * mean;
            const int   i    = r * (63 - r) / 2 + (c - r - 1);
            const float sc   = gamma[i] / sqrtf(var + BN_EPS);
            scale[i] = sc;
            shift[i] = beta[i] - mean * sc;
        }
    }
}

// ---------------- Main: fused normalize * W -> attn -> softmax -> out -------
__global__ __launch_bounds__(256) void main_kernel(
        const float* __restrict__ xi, const float* __restrict__ xj,
        const float* __restrict__ W,
        const float* __restrict__ attn_w, const float* __restrict__ attn_b,
        const float* __restrict__ proj_w, const float* __restrict__ proj_b,
        const float* __restrict__ scale, const float* __restrict__ shift,
        float* __restrict__ out) {
    __shared__ __attribute__((aligned(16))) float xi_l[NF * XPAD];
    __shared__ __attribute__((aligned(16))) float xj_l[NF * XPAD];
    __shared__ float ss_l[NI * 2];
    __shared__ float lg[NI];
    __shared__ int   rc_l[NI];
    __shared__ float redm[4], reds[4];

    const int b = blockIdx.x;
    const int t = threadIdx.x;

    // ---- Phase A: stage xi/xj rows + scale/shift ----
    {
        const float4* x4 = (const float4*)(xi + (size_t)b * NF * NE);
        const float4* y4 = (const float4*)(xj + (size_t)b * NF * NE);
        const int r  = t >> 3;
        const int e0 = (t & 7) * 4;
        *(float4*)&xi_l[r * XPAD + e0] = x4[t];
        *(float4*)&xj_l[r * XPAD + e0] = y4[t];
        for (int s = t; s < NI; s += 256) {
            ss_l[2*s]   = scale[s];
            ss_l[2*s+1] = shift[s];
        }
    }
    __syncthreads();

    const float4* W4  = (const float4*)W;
    const float4* aw4 = (const float4*)attn_w;
    const float4* ab4 = (const float4*)attn_b;
    const float4* pw4 = (const float4*)proj_w;
    const float  pb   = proj_b[0];

    // ---- Phase B: o on the fly, 8 float4 accumulators ----
    #pragma unroll
    for (int round = 0; round < 2; ++round) {
        const int i = t + round * 256;
        if (i < NI) {
            int r, c; pair_rc_fast(i, r, c);
            rc_l[i] = (r << 5) | c;
            const float sc = ss_l[2*i], sh = ss_l[2*i+1];
            const float4* xir = (const float4*)&xi_l[r * XPAD];
            const float4* xjc = (const float4*)&xj_l[c * XPAD];

            float4 wv[8];
            #pragma unroll
            for (int g = 0; g < 8; ++g) wv[g] = W4[i*8 + g];  // prefetch W row

            float4 h[8];
            #pragma unroll
            for (int a4 = 0; a4 < 8; ++a4) h[a4] = ab4[a4];

            #pragma unroll
            for (int g = 0; g < 8; ++g) {
                const float4 av = xir[g];
                const float4 qv = xjc[g];
                float og[4];
                og[0] = wv[g].x * (sc * av.x * qv.x + sh);
                og[1] = wv[g].y * (sc * av.y * qv.y + sh);
                og[2] = wv[g].z * (sc * av.z * qv.z + sh);
                og[3] = wv[g].w * (sc * av.w * qv.w + sh);
                #pragma unroll
                for (int k = 0; k < 4; ++k) {
                    const float s = og[k];
                    const int e = 4*g + k;
                    #pragma unroll
                    for (int a4 = 0; a4 < 8; ++a4) {
                        const float4 wr = aw4[e*8 + a4];   // uniform -> s_load
                        h[a4].x += s * wr.x;
                        h[a4].y += s * wr.y;
                        h[a4].z += s * wr.z;
                        h[a4].w += s * wr.w;
                    }
                }
            }

            float logit = pb;
            #pragma unroll
            for (int a4 = 0; a4 < 8; ++a4) {
                const float4 pw = pw4[a4];
                logit += fmaxf(h[a4].x, 0.f) * pw.x + fmaxf(h[a4].y, 0.f) * pw.y
                       + fmaxf(h[a4].z, 0.f) * pw.z + fmaxf(h[a4].w, 0.f) * pw.w;
            }
            lg[i] = logit;
        }
    }
    __syncthreads();

    // ---- softmax over the 496 interactions (exp computed once) ----
    float m = -1e30f;
    for (int f = t; f < NI; f += 256) m = fmaxf(m, lg[f]);
    for (int off = 32; off; off >>= 1) m = fmaxf(m, __shfl_xor(m, off));
    const int wv_ = t >> 6;
    if ((t & 63) == 0) redm[wv_] = m;
    __syncthreads();
    m = fmaxf(fmaxf(redm[0], redm[1]), fmaxf(redm[2], redm[3]));

    float s = 0.f;
    for (int f = t; f < NI; f += 256) {
        const float e = expf(lg[f] - m);
        lg[f] = e;                       // own slots only; safe to overwrite
        s += e;
    }
    for (int off = 32; off; off >>= 1) s += __shfl_xor(s, off);
    if ((t & 63) == 0) reds[wv_] = s;
    __syncthreads();
    const float inv = 1.0f / ((reds[0] + reds[1]) + (reds[2] + reds[3]));

    for (int f = t; f < NI; f += 256) lg[f] *= inv;
    __syncthreads();

    // ---- Phase C: recompute o, write scores * o (nt float4) ----
    f32x4_t* op4 = (f32x4_t*)(out + (size_t)b * NI * NE);
    for (int f4 = t; f4 < NI * 8; f4 += 256) {
        const int i  = f4 >> 3;
        const int e0 = (f4 & 7) * 4;
        const int rc = rc_l[i];
        const int r  = rc >> 5, c = rc & 31;
        const float sc = ss_l[2*i], sh = ss_l[2*i+1];
        const float score = lg[i];
        const float4 w = W4[f4];
        f32x4_t res;
        res.x = score * (w.x * (sc * xi_l[r*XPAD+e0+0] * xj_l[c*XPAD+e0+0] + sh));
        res.y = score * (w.y * (sc * xi_l[r*XPAD+e0+1] * xj_l[c*XPAD+e0+1] + sh));
        res.z = score * (w.z * (sc * xi_l[r*XPAD+e0+2] * xj_l[c*XPAD+e0+2] + sh));
        res.w = score * (w.w * (sc * xi_l[r*XPAD+e0+3] * xj_l[c*XPAD+e0+3] + sh));
        __builtin_nontemporal_store(res, &op4[f4]);
    }
}

extern "C" void kernel_launch(void* const* d_in, const int* in_sizes, int n_in,
                              void* d_out, int out_size, void* d_ws, size_t ws_size,
                              hipStream_t stream) {
    const float* xi     = (const float*)d_in[0];
    const float* xj     = (const float*)d_in[1];
    const float* W      = (const float*)d_in[2];
    const float* gamma  = (const float*)d_in[3];
    const float* beta   = (const float*)d_in[4];
    const float* attn_w = (const float*)d_in[5];
    const float* attn_b = (const float*)d_in[6];
    const float* proj_w = (const float*)d_in[7];
    const float* proj_b = (const float*)d_in[8];
    float* out = (float*)d_out;

    float* part  = (float*)d_ws;                    // 512 * 2048 floats = 4 MB
    float* scale = part + (size_t)SA_BLOCKS * 2048; // 496 (rounded up below)
    float* shift = scale + 512;

    statsA<<<SA_BLOCKS, 256, 0, stream>>>(xi, xj, part);
    statsB<<<8, 256, 0, stream>>>(part, gamma, beta, scale, shift);
    main_kernel<<<NB, 256, 0, stream>>>(xi, xj, W, attn_w, attn_b,
                                        proj_w, proj_b, scale, shift, out);
}

// Round 5
// 160.074 us; speedup vs baseline: 1.0035x; 1.0035x over previous
//
#include <hip/hip_runtime.h>

#define NB 4096
#define NF 32             // F0 == F1
#define NE 32
#define NI 496            // 32*31/2
#define BN_EPS 1e-5f
#define XPAD 36           // padded row stride (floats) for xi/xj LDS tiles
#define OBP 40            // o_bf row stride in bf16 elems (80 B: 16B-aligned, <=2-way banks)

#define SA_BLOCKS 512
#define SA_BPB    8       // batches per stats block
#define SA_CHUNK  4       // batches staged per LDS pass

typedef float f32x4_t __attribute__((ext_vector_type(4)));
typedef short bf16x8_t __attribute__((ext_vector_type(8)));
typedef unsigned short u16x4_t __attribute__((ext_vector_type(4)));

static __device__ __forceinline__ unsigned short f2bf(float f) {
    unsigned u = __builtin_bit_cast(unsigned, f);
    u = (u + 0x7FFFu + ((u >> 16) & 1u)) >> 16;   // RNE, finite inputs
    return (unsigned short)u;
}

// closed-form pair index: offset(r) = r*(63-r)/2
__device__ __forceinline__ void pair_rc_fast(int i, int& r, int& c) {
    int rr = (int)((63.0f - sqrtf(3969.0f - 8.0f * (float)i)) * 0.5f);
    int off = rr * (63 - rr) / 2;
    if (off > i) { --rr; off = rr * (63 - rr) / 2; }
    else {
        int off2 = (rr + 1) * (62 - rr) / 2;
        if (off2 <= i) { rr = rr + 1; off = off2; }
    }
    r = rr; c = rr + 1 + (i - off);
}

// ---- Stats A: partial Gram matrices G1 = sum xi*xj, G2 = sum xi^2*xj^2 -----
__global__ __launch_bounds__(256) void statsA(
        const float* __restrict__ xi, const float* __restrict__ xj,
        float* __restrict__ part) {
    __shared__ __attribute__((aligned(16))) float xi_l[SA_CHUNK * NF * XPAD];
    __shared__ __attribute__((aligned(16))) float xj_l[SA_CHUNK * NF * XPAD];
    const int t  = threadIdx.x;
    const int r  = t >> 3;
    const int cg = t & 7;

    float4 acc1[4] = {{0,0,0,0},{0,0,0,0},{0,0,0,0},{0,0,0,0}};
    float4 acc2[4] = {{0,0,0,0},{0,0,0,0},{0,0,0,0},{0,0,0,0}};

    for (int ch = 0; ch < SA_BPB / SA_CHUNK; ++ch) {
        const int b0 = blockIdx.x * SA_BPB + ch * SA_CHUNK;
        const float4* xs = (const float4*)(xi + (size_t)b0 * NF * NE);
        const float4* ys = (const float4*)(xj + (size_t)b0 * NF * NE);
        if (ch) __syncthreads();
        #pragma unroll
        for (int k = 0; k < 4; ++k) {
            const int idx = t + 256 * k;
            const int row = idx >> 3;
            const int e4  = idx & 7;
            *(float4*)&xi_l[row * XPAD + e4 * 4] = xs[idx];
            *(float4*)&xj_l[row * XPAD + e4 * 4] = ys[idx];
        }
        __syncthreads();
        #pragma unroll
        for (int bb = 0; bb < SA_CHUNK; ++bb) {
            const float* xr  = &xi_l[(bb * NF + r) * XPAD];
            const float* xc0 = &xj_l[(bb * NF) * XPAD];
            #pragma unroll
            for (int e4 = 0; e4 < 8; ++e4) {
                const float4 av = *(const float4*)&xr[e4 * 4];
                #pragma unroll
                for (int k = 0; k < 4; ++k) {
                    const int c = cg + 8 * k;
                    const float4 qv = *(const float4*)&xc0[c * XPAD + e4 * 4];
                    float px = av.x * qv.x, py = av.y * qv.y;
                    float pz = av.z * qv.z, pw = av.w * qv.w;
                    acc1[k].x += px; acc1[k].y += py;
                    acc1[k].z += pz; acc1[k].w += pw;
                    acc2[k].x += px * px; acc2[k].y += py * py;
                    acc2[k].z += pz * pz; acc2[k].w += pw * pw;
                }
            }
        }
    }

    float* dst = part + (size_t)blockIdx.x * 2048;
    #pragma unroll
    for (int k = 0; k < 4; ++k) {
        const int c = cg + 8 * k;
        const int j = r * 32 + c;
        float g1 = (acc1[k].x + acc1[k].y) + (acc1[k].z + acc1[k].w);
        float g2 = (acc2[k].x + acc2[k].y) + (acc2[k].z + acc2[k].w);
        *(float2*)&dst[2 * j] = make_float2(g1, g2);
    }
}

// ---- Stats B: reduce partials + finalize scale/shift (32 blocks) -----------
__global__ __launch_bounds__(256) void statsB(
        const float* __restrict__ part,
        const float* __restrict__ gamma, const float* __restrict__ beta,
        float* __restrict__ scale, float* __restrict__ shift) {
    __shared__ float red[256];
    const int t   = threadIdx.x;
    const int col = blockIdx.x * 64 + (t & 63);   // float column 0..2047
    const int q   = t >> 6;                       // partial quarter 0..3
    float s = 0.f;
    #pragma unroll 8
    for (int p = q * 128; p < (q + 1) * 128; ++p)
        s += part[(size_t)p * 2048 + col];
    red[t] = s;
    __syncthreads();
    if (t < 64) red[t] = red[t] + red[t + 64] + red[t + 128] + red[t + 192];
    __syncthreads();
    if (t < 32) {
        const int cell = blockIdx.x * 32 + t;     // rc cell 0..1023
        const int r = cell >> 5, c = cell & 31;
        if (c > r) {
            const float g1 = red[2 * t];
            const float g2 = red[2 * t + 1];
            const float invN = 1.0f / (float)(NB * NE);
            const float mean = g1 * invN;
            const float var  = g2 * invN - mean * mean;
            const int   i    = r * (63 - r) / 2 + (c - r - 1);
            const float sc   = gamma[i] / sqrtf(var + BN_EPS);
            scale[i] = sc;
            shift[i] = beta[i] - mean * sc;
        }
    }
}

// ---------------- Main: o -> bf16 MFMA logits -> softmax -> out -------------
__global__ __launch_bounds__(256) void main_kernel(
        const float* __restrict__ xi, const float* __restrict__ xj,
        const float* __restrict__ W,
        const float* __restrict__ attn_w, const float* __restrict__ attn_b,
        const float* __restrict__ proj_w, const float* __restrict__ proj_b,
        const float* __restrict__ scale, const float* __restrict__ shift,
        float* __restrict__ out) {
    __shared__ __attribute__((aligned(16))) float xi_l[NF * XPAD];
    __shared__ __attribute__((aligned(16))) float xj_l[NF * XPAD];
    __shared__ __attribute__((aligned(16))) unsigned short o_bf[NI * OBP];
    __shared__ float ss_l[NI * 2];
    __shared__ float lg[NI];
    __shared__ int   rc_l[NI];
    __shared__ float redm[4], reds[4];

    const int b    = blockIdx.x;
    const int t    = threadIdx.x;
    const int lane = t & 63;
    const int wv   = t >> 6;

    // ---- Phase A: stage xi/xj + scale/shift + pair indices ----
    {
        const float4* x4 = (const float4*)(xi + (size_t)b * NF * NE);
        const float4* y4 = (const float4*)(xj + (size_t)b * NF * NE);
        const int r  = t >> 3;
        const int e0 = (t & 7) * 4;
        *(float4*)&xi_l[r * XPAD + e0] = x4[t];
        *(float4*)&xj_l[r * XPAD + e0] = y4[t];
        for (int s = t; s < NI; s += 256) {
            ss_l[2*s]   = scale[s];
            ss_l[2*s+1] = shift[s];
            int rr, cc; pair_rc_fast(s, rr, cc);
            rc_l[s] = (rr << 5) | cc;
        }
    }

    // ---- Build MFMA B-fragments from attn_w (per-lane, global reads) ----
    // B[k][n] = attn_w[k*NE + n]; lane: n = lane&15 (+16 for tile1), k = (lane>>4)*8 + j
    bf16x8_t bf0, bf1;
    {
        const int n  = lane & 15;
        const int kc = (lane >> 4) * 8;
        #pragma unroll
        for (int j = 0; j < 8; ++j) {
            bf0[j] = (short)f2bf(attn_w[(kc + j) * NE + n]);
            bf1[j] = (short)f2bf(attn_w[(kc + j) * NE + n + 16]);
        }
    }
    const float abn0 = attn_b[lane & 15];
    const float abn1 = attn_b[(lane & 15) + 16];
    const float pwn0 = proj_w[lane & 15];
    const float pwn1 = proj_w[(lane & 15) + 16];
    const float pb   = proj_b[0];
    __syncthreads();

    // ---- Phase B: o fp32 -> bf16 A-tiles in LDS ----
    const float4* W4 = (const float4*)W;
    for (int f4 = t; f4 < NI * 8; f4 += 256) {
        const int i  = f4 >> 3;
        const int e0 = (f4 & 7) * 4;
        const int rc = rc_l[i];
        const int r  = rc >> 5, c = rc & 31;
        const float sc = ss_l[2*i], sh = ss_l[2*i+1];
        const float4 w = W4[f4];
        const float4 a = *(const float4*)&xi_l[r*XPAD + e0];
        const float4 q = *(const float4*)&xj_l[c*XPAD + e0];
        u16x4_t pk;
        pk.x = f2bf(w.x * (sc * a.x * q.x + sh));
        pk.y = f2bf(w.y * (sc * a.y * q.y + sh));
        pk.z = f2bf(w.z * (sc * a.z * q.z + sh));
        pk.w = f2bf(w.w * (sc * a.w * q.w + sh));
        *(u16x4_t*)&o_bf[i * OBP + e0] = pk;
    }
    __syncthreads();

    // ---- Phase C: 31 M-tiles x 2 MFMA -> logits ----
    for (int m = wv; m < 31; m += 4) {
        const int arow = m * 16 + (lane & 15);
        bf16x8_t af = *(const bf16x8_t*)&o_bf[arow * OBP + (lane >> 4) * 8];
        f32x4_t c0 = {0.f, 0.f, 0.f, 0.f};
        f32x4_t c1 = {0.f, 0.f, 0.f, 0.f};
        c0 = __builtin_amdgcn_mfma_f32_16x16x32_bf16(af, bf0, c0, 0, 0, 0);
        c1 = __builtin_amdgcn_mfma_f32_16x16x32_bf16(af, bf1, c1, 0, 0, 0);
        #pragma unroll
        for (int j = 0; j < 4; ++j) {
            float v = fmaxf(c0[j] + abn0, 0.f) * pwn0
                    + fmaxf(c1[j] + abn1, 0.f) * pwn1;
            v += __shfl_xor(v, 1);
            v += __shfl_xor(v, 2);
            v += __shfl_xor(v, 4);
            v += __shfl_xor(v, 8);
            if ((lane & 15) == 0)
                lg[m * 16 + (lane >> 4) * 4 + j] = v + pb;
        }
    }
    __syncthreads();

    // ---- softmax over the 496 interactions ----
    float m = -1e30f;
    for (int f = t; f < NI; f += 256) m = fmaxf(m, lg[f]);
    for (int off = 32; off; off >>= 1) m = fmaxf(m, __shfl_xor(m, off));
    if ((t & 63) == 0) redm[wv] = m;
    __syncthreads();
    m = fmaxf(fmaxf(redm[0], redm[1]), fmaxf(redm[2], redm[3]));

    float s = 0.f;
    for (int f = t; f < NI; f += 256) {
        const float e = expf(lg[f] - m);
        lg[f] = e;
        s += e;
    }
    for (int off = 32; off; off >>= 1) s += __shfl_xor(s, off);
    if ((t & 63) == 0) reds[wv] = s;
    __syncthreads();
    const float inv = 1.0f / ((reds[0] + reds[1]) + (reds[2] + reds[3]));

    for (int f = t; f < NI; f += 256) lg[f] *= inv;
    __syncthreads();

    // ---- Phase D: recompute o fp32, write scores * o (nt float4) ----
    f32x4_t* op4 = (f32x4_t*)(out + (size_t)b * NI * NE);
    for (int f4 = t; f4 < NI * 8; f4 += 256) {
        const int i  = f4 >> 3;
        const int e0 = (f4 & 7) * 4;
        const int rc = rc_l[i];
        const int r  = rc >> 5, c = rc & 31;
        const float sc = ss_l[2*i], sh = ss_l[2*i+1];
        const float score = lg[i];
        const float4 w = W4[f4];
        f32x4_t res;
        res.x = score * (w.x * (sc * xi_l[r*XPAD+e0+0] * xj_l[c*XPAD+e0+0] + sh));
        res.y = score * (w.y * (sc * xi_l[r*XPAD+e0+1] * xj_l[c*XPAD+e0+1] + sh));
        res.z = score * (w.z * (sc * xi_l[r*XPAD+e0+2] * xj_l[c*XPAD+e0+2] + sh));
        res.w = score * (w.w * (sc * xi_l[r*XPAD+e0+3] * xj_l[c*XPAD+e0+3] + sh));
        __builtin_nontemporal_store(res, &op4[f4]);
    }
}

extern "C" void kernel_launch(void* const* d_in, const int* in_sizes, int n_in,
                              void* d_out, int out_size, void* d_ws, size_t ws_size,
                              hipStream_t stream) {
    const float* xi     = (const float*)d_in[0];
    const float* xj     = (const float*)d_in[1];
    const float* W      = (const float*)d_in[2];
    const float* gamma  = (const float*)d_in[3];
    const float* beta   = (const float*)d_in[4];
    const float* attn_w = (const float*)d_in[5];
    const float* attn_b = (const float*)d_in[6];
    const float* proj_w = (const float*)d_in[7];
    const float* proj_b = (const float*)d_in[8];
    float* out = (float*)d_out;

    float* part  = (float*)d_ws;                    // 512 * 2048 floats = 4 MB
    float* scale = part + (size_t)SA_BLOCKS * 2048;
    float* shift = scale + 512;

    statsA<<<SA_BLOCKS, 256, 0, stream>>>(xi, xj, part);
    statsB<<<32, 256, 0, stream>>>(part, gamma, beta, scale, shift);
    main_kernel<<<NB, 256, 0, stream>>>(xi, xj, W, attn_w, attn_b,
                                        proj_w, proj_b, scale, shift, out);
}

// Round 6
// 122.395 us; speedup vs baseline: 1.3124x; 1.3078x over previous
//
#include <hip/hip_runtime.h>

#define NB 4096
#define NF 32             // F0 == F1
#define NE 32
#define NI 496            // 32*31/2
#define BN_EPS 1e-5f
#define XPAD 36           // padded row stride (floats) for xi/xj LDS tiles

#define SA_BLOCKS 512
#define SA_BPB    8       // batches per stats block
#define SA_CHUNK  4       // batches staged per LDS pass

typedef float f32x4_t __attribute__((ext_vector_type(4)));
typedef short bf16x8_t __attribute__((ext_vector_type(8)));

static __device__ __forceinline__ unsigned short f2bf(float f) {
    unsigned u = __builtin_bit_cast(unsigned, f);
    u = (u + 0x7FFFu + ((u >> 16) & 1u)) >> 16;   // RNE, finite inputs
    return (unsigned short)u;
}

// closed-form pair index: offset(r) = r*(63-r)/2
__device__ __forceinline__ void pair_rc_fast(int i, int& r, int& c) {
    int rr = (int)((63.0f - sqrtf(3969.0f - 8.0f * (float)i)) * 0.5f);
    int off = rr * (63 - rr) / 2;
    if (off > i) { --rr; off = rr * (63 - rr) / 2; }
    else {
        int off2 = (rr + 1) * (62 - rr) / 2;
        if (off2 <= i) { rr = rr + 1; off = off2; }
    }
    r = rr; c = rr + 1 + (i - off);
}

// ---- Stats A: partial Gram matrices G1 = sum xi*xj, G2 = sum xi^2*xj^2 -----
__global__ __launch_bounds__(256) void statsA(
        const float* __restrict__ xi, const float* __restrict__ xj,
        float* __restrict__ part) {
    __shared__ __attribute__((aligned(16))) float xi_l[SA_CHUNK * NF * XPAD];
    __shared__ __attribute__((aligned(16))) float xj_l[SA_CHUNK * NF * XPAD];
    const int t  = threadIdx.x;
    const int r  = t >> 3;
    const int cg = t & 7;

    float4 acc1[4] = {{0,0,0,0},{0,0,0,0},{0,0,0,0},{0,0,0,0}};
    float4 acc2[4] = {{0,0,0,0},{0,0,0,0},{0,0,0,0},{0,0,0,0}};

    for (int ch = 0; ch < SA_BPB / SA_CHUNK; ++ch) {
        const int b0 = blockIdx.x * SA_BPB + ch * SA_CHUNK;
        const float4* xs = (const float4*)(xi + (size_t)b0 * NF * NE);
        const float4* ys = (const float4*)(xj + (size_t)b0 * NF * NE);
        if (ch) __syncthreads();
        #pragma unroll
        for (int k = 0; k < 4; ++k) {
            const int idx = t + 256 * k;
            const int row = idx >> 3;
            const int e4  = idx & 7;
            *(float4*)&xi_l[row * XPAD + e4 * 4] = xs[idx];
            *(float4*)&xj_l[row * XPAD + e4 * 4] = ys[idx];
        }
        __syncthreads();
        #pragma unroll
        for (int bb = 0; bb < SA_CHUNK; ++bb) {
            const float* xr  = &xi_l[(bb * NF + r) * XPAD];
            const float* xc0 = &xj_l[(bb * NF) * XPAD];
            #pragma unroll
            for (int e4 = 0; e4 < 8; ++e4) {
                const float4 av = *(const float4*)&xr[e4 * 4];
                #pragma unroll
                for (int k = 0; k < 4; ++k) {
                    const int c = cg + 8 * k;
                    const float4 qv = *(const float4*)&xc0[c * XPAD + e4 * 4];
                    float px = av.x * qv.x, py = av.y * qv.y;
                    float pz = av.z * qv.z, pw = av.w * qv.w;
                    acc1[k].x += px; acc1[k].y += py;
                    acc1[k].z += pz; acc1[k].w += pw;
                    acc2[k].x += px * px; acc2[k].y += py * py;
                    acc2[k].z += pz * pz; acc2[k].w += pw * pw;
                }
            }
        }
    }

    float* dst = part + (size_t)blockIdx.x * 2048;
    #pragma unroll
    for (int k = 0; k < 4; ++k) {
        const int c = cg + 8 * k;
        const int j = r * 32 + c;
        float g1 = (acc1[k].x + acc1[k].y) + (acc1[k].z + acc1[k].w);
        float g2 = (acc2[k].x + acc2[k].y) + (acc2[k].z + acc2[k].w);
        *(float2*)&dst[2 * j] = make_float2(g1, g2);
    }
}

// ---- Stats B: reduce partials + finalize scale/shift (32 blocks) -----------
__global__ __launch_bounds__(256) void statsB(
        const float* __restrict__ part,
        const float* __restrict__ gamma, const float* __restrict__ beta,
        float* __restrict__ scale, float* __restrict__ shift) {
    __shared__ float red[256];
    const int t   = threadIdx.x;
    const int col = blockIdx.x * 64 + (t & 63);
    const int q   = t >> 6;
    float s = 0.f;
    #pragma unroll 8
    for (int p = q * 128; p < (q + 1) * 128; ++p)
        s += part[(size_t)p * 2048 + col];
    red[t] = s;
    __syncthreads();
    if (t < 64) red[t] = red[t] + red[t + 64] + red[t + 128] + red[t + 192];
    __syncthreads();
    if (t < 32) {
        const int cell = blockIdx.x * 32 + t;
        const int r = cell >> 5, c = cell & 31;
        if (c > r) {
            const float g1 = red[2 * t];
            const float g2 = red[2 * t + 1];
            const float invN = 1.0f / (float)(NB * NE);
            const float mean = g1 * invN;
            const float var  = g2 * invN - mean * mean;
            const int   i    = r * (63 - r) / 2 + (c - r - 1);
            const float sc   = gamma[i] / sqrtf(var + BN_EPS);
            scale[i] = sc;
            shift[i] = beta[i] - mean * sc;
        }
    }
}

// ---------------- Main: in-reg A-frag MFMA logits -> softmax -> out ---------
__global__ __launch_bounds__(256) void main_kernel(
        const float* __restrict__ xi, const float* __restrict__ xj,
        const float* __restrict__ W,
        const float* __restrict__ attn_w, const float* __restrict__ attn_b,
        const float* __restrict__ proj_w, const float* __restrict__ proj_b,
        const float* __restrict__ scale, const float* __restrict__ shift,
        float* __restrict__ out) {
    __shared__ __attribute__((aligned(16))) float xi_l[NF * XPAD];
    __shared__ __attribute__((aligned(16))) float xj_l[NF * XPAD];
    __shared__ float ss_l[NI * 2];
    __shared__ float lg[NI];
    __shared__ int   rc_l[NI];
    __shared__ float redm[4], reds[4];

    const int b    = blockIdx.x;
    const int t    = threadIdx.x;
    const int lane = t & 63;
    const int wv   = t >> 6;

    // ---- Phase A: stage xi/xj + scale/shift + pair indices ----
    {
        const float4* x4 = (const float4*)(xi + (size_t)b * NF * NE);
        const float4* y4 = (const float4*)(xj + (size_t)b * NF * NE);
        const int r  = t >> 3;
        const int e0 = (t & 7) * 4;
        *(float4*)&xi_l[r * XPAD + e0] = x4[t];
        *(float4*)&xj_l[r * XPAD + e0] = y4[t];
        for (int s = t; s < NI; s += 256) {
            ss_l[2*s]   = scale[s];
            ss_l[2*s+1] = shift[s];
            int rr, cc; pair_rc_fast(s, rr, cc);
            rc_l[s] = (rr << 5) | cc;
        }
    }

    // ---- B-fragments from attn_w: lane n = lane&15, k = (lane>>4)*8 + j ----
    bf16x8_t bfr0, bfr1;
    {
        const int n  = lane & 15;
        const int kc = (lane >> 4) * 8;
        #pragma unroll
        for (int j = 0; j < 8; ++j) {
            bfr0[j] = (short)f2bf(attn_w[(kc + j) * NE + n]);
            bfr1[j] = (short)f2bf(attn_w[(kc + j) * NE + n + 16]);
        }
    }
    const float abn0 = attn_b[lane & 15];
    const float abn1 = attn_b[(lane & 15) + 16];
    const float pwn0 = proj_w[lane & 15];
    const float pwn1 = proj_w[(lane & 15) + 16];
    const float pb   = proj_b[0];
    __syncthreads();

    // ---- Phase C: per m-tile, build A-frag in registers, 2 MFMA, logits ----
    for (int m = wv; m < 31; m += 4) {
        const int i  = m * 16 + (lane & 15);       // interaction row
        const int kc = (lane >> 4) * 8;            // k-chunk 0/8/16/24
        const int rc = rc_l[i];
        const int r  = rc >> 5, c = rc & 31;
        const float sc = ss_l[2*i], sh = ss_l[2*i+1];
        const float4 a0 = *(const float4*)&xi_l[r * XPAD + kc];
        const float4 a1 = *(const float4*)&xi_l[r * XPAD + kc + 4];
        const float4 q0 = *(const float4*)&xj_l[c * XPAD + kc];
        const float4 q1 = *(const float4*)&xj_l[c * XPAD + kc + 4];
        const float4 w0 = *(const float4*)&W[i * NE + kc];
        const float4 w1 = *(const float4*)&W[i * NE + kc + 4];
        bf16x8_t af;
        af[0] = (short)f2bf(w0.x * (sc * a0.x * q0.x + sh));
        af[1] = (short)f2bf(w0.y * (sc * a0.y * q0.y + sh));
        af[2] = (short)f2bf(w0.z * (sc * a0.z * q0.z + sh));
        af[3] = (short)f2bf(w0.w * (sc * a0.w * q0.w + sh));
        af[4] = (short)f2bf(w1.x * (sc * a1.x * q1.x + sh));
        af[5] = (short)f2bf(w1.y * (sc * a1.y * q1.y + sh));
        af[6] = (short)f2bf(w1.z * (sc * a1.z * q1.z + sh));
        af[7] = (short)f2bf(w1.w * (sc * a1.w * q1.w + sh));

        f32x4_t c0 = {0.f, 0.f, 0.f, 0.f};
        f32x4_t c1 = {0.f, 0.f, 0.f, 0.f};
        c0 = __builtin_amdgcn_mfma_f32_16x16x32_bf16(af, bfr0, c0, 0, 0, 0);
        c1 = __builtin_amdgcn_mfma_f32_16x16x32_bf16(af, bfr1, c1, 0, 0, 0);
        #pragma unroll
        for (int j = 0; j < 4; ++j) {
            float v = fmaxf(c0[j] + abn0, 0.f) * pwn0
                    + fmaxf(c1[j] + abn1, 0.f) * pwn1;
            v += __shfl_xor(v, 1);
            v += __shfl_xor(v, 2);
            v += __shfl_xor(v, 4);
            v += __shfl_xor(v, 8);
            if ((lane & 15) == 0)
                lg[m * 16 + (lane >> 4) * 4 + j] = v + pb;
        }
    }
    __syncthreads();

    // ---- softmax over the 496 interactions ----
    float m = -1e30f;
    for (int f = t; f < NI; f += 256) m = fmaxf(m, lg[f]);
    for (int off = 32; off; off >>= 1) m = fmaxf(m, __shfl_xor(m, off));
    if ((t & 63) == 0) redm[wv] = m;
    __syncthreads();
    m = fmaxf(fmaxf(redm[0], redm[1]), fmaxf(redm[2], redm[3]));

    float s = 0.f;
    for (int f = t; f < NI; f += 256) {
        const float e = expf(lg[f] - m);
        lg[f] = e;
        s += e;
    }
    for (int off = 32; off; off >>= 1) s += __shfl_xor(s, off);
    if ((t & 63) == 0) reds[wv] = s;
    __syncthreads();
    const float inv = 1.0f / ((reds[0] + reds[1]) + (reds[2] + reds[3]));

    for (int f = t; f < NI; f += 256) lg[f] *= inv;
    __syncthreads();

    // ---- Phase D: recompute o fp32, write scores * o (plain float4) ----
    const float4* W4 = (const float4*)W;
    float4* op4 = (float4*)(out + (size_t)b * NI * NE);
    for (int f4 = t; f4 < NI * 8; f4 += 256) {
        const int i  = f4 >> 3;
        const int e0 = (f4 & 7) * 4;
        const int rc = rc_l[i];
        const int r  = rc >> 5, c = rc & 31;
        const float sc = ss_l[2*i], sh = ss_l[2*i+1];
        const float score = lg[i];
        const float4 w = W4[f4];
        float4 res;
        res.x = score * (w.x * (sc * xi_l[r*XPAD+e0+0] * xj_l[c*XPAD+e0+0] + sh));
        res.y = score * (w.y * (sc * xi_l[r*XPAD+e0+1] * xj_l[c*XPAD+e0+1] + sh));
        res.z = score * (w.z * (sc * xi_l[r*XPAD+e0+2] * xj_l[c*XPAD+e0+2] + sh));
        res.w = score * (w.w * (sc * xi_l[r*XPAD+e0+3] * xj_l[c*XPAD+e0+3] + sh));
        op4[f4] = res;
    }
}

extern "C" void kernel_launch(void* const* d_in, const int* in_sizes, int n_in,
                              void* d_out, int out_size, void* d_ws, size_t ws_size,
                              hipStream_t stream) {
    const float* xi     = (const float*)d_in[0];
    const float* xj     = (const float*)d_in[1];
    const float* W      = (const float*)d_in[2];
    const float* gamma  = (const float*)d_in[3];
    const float* beta   = (const float*)d_in[4];
    const float* attn_w = (const float*)d_in[5];
    const float* attn_b = (const float*)d_in[6];
    const float* proj_w = (const float*)d_in[7];
    const float* proj_b = (const float*)d_in[8];
    float* out = (float*)d_out;

    float* part  = (float*)d_ws;                    // 512 * 2048 floats = 4 MB
    float* scale = part + (size_t)SA_BLOCKS * 2048;
    float* shift = scale + 512;

    statsA<<<SA_BLOCKS, 256, 0, stream>>>(xi, xj, part);
    statsB<<<32, 256, 0, stream>>>(part, gamma, beta, scale, shift);
    main_kernel<<<NB, 256, 0, stream>>>(xi, xj, W, attn_w, attn_b,
                                        proj_w, proj_b, scale, shift, out);
}